// Round 10
// baseline (444.641 us; speedup 1.0000x reference)
//
#include <hip/hip_runtime.h>

typedef unsigned short u16;
typedef __attribute__((ext_vector_type(4))) unsigned short u16x4;
typedef __attribute__((ext_vector_type(8))) unsigned short u16x8;
typedef __attribute__((ext_vector_type(4))) float f32x4;
typedef __attribute__((ext_vector_type(8))) __bf16 bf16x8;
typedef __attribute__((ext_vector_type(2))) unsigned int u32x2;
typedef __attribute__((ext_vector_type(4))) unsigned int u32x4;

// ---- workspace layout (bytes) ----
#define WS_XH    0UL          // hidden bf16 [8192][512]; dead after QKV GEMMs -> reused as CTXIB
#define WS_XT    8388608UL    // text bf16; dead after QKV GEMMs -> reused as CTXTB
#define WS_W     16777216UL   // all weights bf16, contiguous (see prep_weights)
#define WS_BQI   24117248UL   // concat bias qkv_img fp32 [1536]
#define WS_BQT   24123392UL   // concat bias qkv_txt fp32 [1536]
#define WS_QKVI  24129536UL   // qkv_img bf16 [8192][1536] (V cols never written; Q pre-scaled)
#define WS_QKVT  49295360UL   // qkv_txt bf16
#define WS_VTI   74461184UL   // v_img^T bf16 [8*8*64][1024]  (written by GEMM epilogue)
#define WS_VTT   82849792UL   // v_txt^T
#define WS_CTXIA 91238400UL   // ctx img, img-key phase, bf16 [8192][512] (*0.5)
#define WS_CTXTA 99627008UL   // ctx txt, txt-key phase
#define WS_OCAT  108015616UL  // concat out bf16 [8192][1024]
// reuse of QKV_I/QKV_T region after attentions complete:
#define WS_OUT2  24129536UL   // out after w_cat bf16 [8192][512]
#define WS_QKVP  32518144UL   // pooled qkv bf16 [8192][1536]
#define WS_VTP   57683968UL   // v_pool^T
#define WS_CTXP  66072576UL   // ctx_pool bf16 [8192][512]

#define SCALE_LOG2E_O8 0.18033688011112042f  // log2(e)/8

__device__ __forceinline__ u16 f2bf(float f) {
  unsigned u = __float_as_uint(f);
  u += 0x7fffu + ((u >> 16) & 1u);   // RNE
  return (u16)(u >> 16);
}
__device__ __forceinline__ float bf2f(u16 v) {
  return __uint_as_float(((unsigned)v) << 16);
}
__device__ __forceinline__ bf16x8 as_bf(u16x8 v) { return __builtin_bit_cast(bf16x8, v); }
__device__ __forceinline__ f32x4 mfma16(bf16x8 a, bf16x8 b, f32x4 c) {
  return __builtin_amdgcn_mfma_f32_16x16x32_bf16(a, b, c, 0, 0, 0);
}
// pack two fp32 into one u32 holding two bf16 (round-half-up)
__device__ __forceinline__ unsigned pack_bf2(float lo, float hi) {
  unsigned a = __float_as_uint(lo) + 0x8000u;
  unsigned b = __float_as_uint(hi) + 0x8000u;
  return __builtin_amdgcn_perm(b, a, 0x07060302);
}

// ---------------- fp32 -> bf16 activation convert ----------------
__global__ __launch_bounds__(256) void cvt_f32_bf16(const float* __restrict__ s,
                                                    u16* __restrict__ d, int n) {
  int i = (blockIdx.x * 256 + threadIdx.x) * 4;
  if (i >= n) return;
  float4 v = *(const float4*)(s + i);
  u16x4 o;
  o[0] = f2bf(v.x); o[1] = f2bf(v.y); o[2] = f2bf(v.z); o[3] = f2bf(v.w);
  *(u16x4*)(d + i) = o;
}

// ---------------- weight prep: convert+concat all weights / biases ----------------
__global__ __launch_bounds__(256) void prep_weights(
    const float* __restrict__ wqi, const float* __restrict__ wki, const float* __restrict__ wvi,
    const float* __restrict__ wqt, const float* __restrict__ wkt, const float* __restrict__ wvt,
    const float* __restrict__ woi, const float* __restrict__ wot,
    const float* __restrict__ wc,  const float* __restrict__ wip, const float* __restrict__ wop,
    const float* __restrict__ bqi, const float* __restrict__ bki, const float* __restrict__ bvi,
    const float* __restrict__ bqt, const float* __restrict__ bkt, const float* __restrict__ bvt,
    u16* __restrict__ wdst, float* __restrict__ bi, float* __restrict__ bt) {
  int i = blockIdx.x * 256 + threadIdx.x;
  if (i < 786432) {
    const float* s = i < 262144 ? wqi : (i < 524288 ? wki : wvi);
    wdst[i] = f2bf(s[i & 262143]);
  } else if (i < 1572864) {
    int j = i - 786432;
    const float* s = j < 262144 ? wqt : (j < 524288 ? wkt : wvt);
    wdst[i] = f2bf(s[j & 262143]);
  } else if (i < 1835008) wdst[i] = f2bf(woi[i - 1572864]);
  else if (i < 2097152)   wdst[i] = f2bf(wot[i - 1835008]);
  else if (i < 2621440)   wdst[i] = f2bf(wc [i - 2097152]);
  else if (i < 3407872)   wdst[i] = f2bf(wip[i - 2621440]);
  else if (i < 3670016)   wdst[i] = f2bf(wop[i - 3407872]);
  else if (i < 3671552) {
    int j = i - 3670016;
    bi[j] = j < 512 ? bqi[j] : (j < 1024 ? bki[j - 512] : bvi[j - 1024]);
  } else if (i < 3673088) {
    int j = i - 3671552;
    bt[j] = j < 512 ? bqt[j] : (j < 1024 ? bkt[j - 512] : bvt[j - 1024]);
  }
}

// ---------------- GEMM: C[M,N] = (A [+ A2])[M,K](bf16) @ W[N,K]^T + bias(f32) ----------------
// Templated tile: WF frags (16-units) per wave per dim; 4 waves as 2x2 -> tile (32*WF)^2.
// WF=4: 128x128 (QKV/in_proj, grid 3/CU). WF=2: 64x64 -> small N=512 GEMMs get 1024
// blocks = 4 blocks/CU (R9 lesson: 1 block/CU is latency-bound with nothing to cover the
// barrier+prefetch chain). Register staging + double-buffered LDS, one barrier per K-iter;
// prefetched register loads fly across the compute phase (R7/R8 lesson: global_load_lds
// drains vmcnt(0) at the barrier, registers don't).
// Permuted lane-linear LDS layout: block b = 16 rows x 32k, chunk = lane*16B; writes and
// fragment reads both lane-linear b128, conflict-free.
// vtout (WF=4, nullable): column tiles n0>=1024 (V third of QKV) stored TRANSPOSED to
// vtout[(b*8+h)*64+d][l] (C-layout regs = 4 consecutive VT cols) -- kills transpose pass.
// A2 (nullable): elementwise bf16 add merged at commit. Columns < qcols scaled by qscale
// in fp32 before bf16 quantize. f32out: fp32 C (d_out dtype).
template <int WF>
__global__ __launch_bounds__(256) void gemm_bf16(
    const u16* __restrict__ A, const u16* __restrict__ A2, int lda,
    const u16* __restrict__ W,
    const float* __restrict__ bias, u16* __restrict__ C, int ldc, int coff, int K,
    int f32out, int qcols, float qscale, u16* __restrict__ vtout) {
  constexpr int NB = WF / 2;              // staged 16-row blocks per wave per operand
  __shared__ __align__(16) u16 As[2][2 * WF * 512];
  __shared__ __align__(16) u16 Bs[2][2 * WF * 512];
  const int tid = threadIdx.x, lane = tid & 63, wv = tid >> 6;
  const int wm = wv >> 1, wn = wv & 1;
  const int ln15 = lane & 15;
  const int m0 = blockIdx.x * (32 * WF), n0 = blockIdx.y * (32 * WF);

  const int srow = lane & 15, skc = lane >> 4;
  const u16* gA[NB];
  const u16* gW[NB];
  const u16* gA2[NB];
#pragma unroll
  for (int c = 0; c < NB; ++c) {
    gA[c] = A + (long)(m0 + wv * (16 * NB) + c * 16 + srow) * lda + skc * 8;
    gW[c] = W + (long)(n0 + wv * (16 * NB) + c * 16 + srow) * K + skc * 8;
    gA2[c] = A2 + (long)(m0 + wv * (16 * NB) + c * 16 + srow) * lda + skc * 8;  // if A2
  }

  f32x4 acc[WF][WF];
#pragma unroll
  for (int j = 0; j < WF; ++j) {
    float bv = bias[n0 + wn * (16 * WF) + j * 16 + ln15];
#pragma unroll
    for (int i = 0; i < WF; ++i) acc[i][j] = f32x4{bv, bv, bv, bv};
  }

  // prologue: tile 0 into registers
  u16x8 ra[NB], rb[NB], rc[NB];
#pragma unroll
  for (int c = 0; c < NB; ++c) {
    ra[c] = *(const u16x8*)(gA[c]);
    rb[c] = *(const u16x8*)(gW[c]);
    if (A2) rc[c] = *(const u16x8*)(gA2[c]);
  }

  int buf = 0;
  for (int k0 = 0; k0 < K; k0 += 32, buf ^= 1) {
#pragma unroll
    for (int c = 0; c < NB; ++c) {
      u16x8 wa = ra[c];
      if (A2) {
#pragma unroll
        for (int u = 0; u < 8; ++u) wa[u] = f2bf(bf2f(ra[c][u]) + bf2f(rc[c][u]));
      }
      *(u16x8*)(As[buf] + (wv * NB + c) * 512 + lane * 8) = wa;
      *(u16x8*)(Bs[buf] + (wv * NB + c) * 512 + lane * 8) = rb[c];
    }
    if (k0 + 32 < K) {
#pragma unroll
      for (int c = 0; c < NB; ++c) {
        ra[c] = *(const u16x8*)(gA[c] + k0 + 32);
        rb[c] = *(const u16x8*)(gW[c] + k0 + 32);
        if (A2) rc[c] = *(const u16x8*)(gA2[c] + k0 + 32);
      }
    }
    __syncthreads();

    bf16x8 af[WF], bfr[WF];
#pragma unroll
    for (int i = 0; i < WF; ++i)
      af[i] = as_bf(*(const u16x8*)(As[buf] + (wm * WF + i) * 512 + lane * 8));
#pragma unroll
    for (int j = 0; j < WF; ++j)
      bfr[j] = as_bf(*(const u16x8*)(Bs[buf] + (wn * WF + j) * 512 + lane * 8));
#pragma unroll
    for (int i = 0; i < WF; ++i)
#pragma unroll
      for (int j = 0; j < WF; ++j) acc[i][j] = mfma16(af[i], bfr[j], acc[i][j]);
  }
  // epilogue: C/D layout col=lane&15, row=quad*4+reg (m89/m91 verified)
  const int quad = lane >> 4;
  const int qr4 = quad * 4;
  if (WF == 4 && vtout && n0 >= 1024) {
    // V tile -> transposed store into VT[(b*8+h)*64+d][l]
#pragma unroll
    for (int j = 0; j < WF; ++j) {
      int col = n0 + wn * (16 * WF) + j * 16 + ln15;    // 1024..1535
      int dg = col - 1024;
#pragma unroll
      for (int i = 0; i < WF; ++i) {
        int row0 = m0 + wm * (16 * WF) + i * 16 + qr4;  // 4 consecutive C-rows = 4 VT cols
        long vr = ((long)(row0 >> 10) * 8 + (dg >> 6)) * 64 + (dg & 63);
        u16x4 ov;
#pragma unroll
        for (int r = 0; r < 4; ++r) ov[r] = f2bf(acc[i][j][r]);
        *(u16x4*)(vtout + vr * 1024 + (row0 & 1023)) = ov;
      }
    }
    return;
  }
  float colsc[WF];
#pragma unroll
  for (int j = 0; j < WF; ++j)
    colsc[j] = (n0 + wn * (16 * WF) + j * 16 < qcols) ? qscale : 1.0f;
#pragma unroll
  for (int i = 0; i < WF; ++i)
#pragma unroll
    for (int r = 0; r < 4; ++r) {
      int row = m0 + wm * (16 * WF) + i * 16 + qr4 + r;
      long cidx = (long)row * ldc + coff + n0 + wn * (16 * WF) + ln15;
      if (f32out) {
        float* cf = (float*)C + cidx;
#pragma unroll
        for (int j = 0; j < WF; ++j) cf[j * 16] = acc[i][j][r] * colsc[j];
      } else {
        u16* cp = C + cidx;
#pragma unroll
        for (int j = 0; j < WF; ++j) cp[j * 16] = f2bf(acc[i][j][r] * colsc[j]);
      }
    }
}

// ---------------- flash attention, S^T formulation: NO P LDS round-trip ----------------
// Compute S^T = K.Q^T (A=K-frag from Kt, B=Q-frag). S^T C-layout (q=ln15, keys=quad*4+r
// per 16-key tile) IS a PV B-fragment under the fixed key permutation
// slot(quad*8+j) <-> key (j<4 ? 4q+j : 16+4q+j-4): P packs entirely in registers.
// PV computes O^T = V^T.P^T, A=V^T b128 from slot-permuted Vt (permutation at staging,
// 2xb64). l = ones.P^T via 1 MFMA (same bf16 P as PV -> bias cancels in O=o/l).
// Phase-split dual (blockIdx.x = qtile|phase). K/V tile k+1 prefetched into registers.
// No-max softmax (Q pre-scaled by log2e/8 at GEMM); raw v_exp_f32.
template <int NQF>
__global__ __launch_bounds__(256) void attn_flash(
    const u16* __restrict__ Q, int ldq,
    const u16* __restrict__ KA, const u16* __restrict__ VTA,
    const u16* __restrict__ KB, const u16* __restrict__ VTB, int ldk,
    u16* __restrict__ OA, u16* __restrict__ OB, int ldo, float outscale) {
  __shared__ __align__(16) u16 Kt[32][72];   // K tile, natural key order [key][d]
  __shared__ __align__(16) u16 Vt[64][40];   // V^T tile, slot-permuted key order [d][slot]
  const int tid = threadIdx.x, lane = tid & 63, wv = tid >> 6;
  const int ln15 = lane & 15, quad = lane >> 4, q8 = quad * 8;
  const int h = blockIdx.y, b = blockIdx.z;

  const u16 *K, *VT;
  u16* O;
  int qtile;
  if (KB != nullptr) {
    qtile = blockIdx.x >> 1;
    int phase = blockIdx.x & 1;
    K = phase ? KB : KA;
    VT = phase ? VTB : VTA;
    O = phase ? OB : OA;
  } else {
    qtile = blockIdx.x;
    K = KA; VT = VTA; O = OA;
  }
  const long qrow = (long)b * 1024 + qtile * (NQF * 64) + wv * (NQF * 16);

  // Q fragments (MFMA B operand: n=lane&15=q, k=quad*8+j=d) [qi][d-half]
  bf16x8 qf[NQF][2];
#pragma unroll
  for (int qi = 0; qi < NQF; ++qi) {
    const u16* qp = Q + (qrow + qi * 16 + ln15) * ldq + h * 64;
    qf[qi][0] = as_bf(*(const u16x8*)(qp + q8));
    qf[qi][1] = as_bf(*(const u16x8*)(qp + 32 + q8));
  }

  u16x8 ones_u;
#pragma unroll
  for (int j = 0; j < 8; ++j) ones_u[j] = 0x3F80;  // bf16 1.0
  const bf16x8 onesb = as_bf(ones_u);

  // staging thread->element maps
  const int kk = tid >> 3, dc = (tid & 7) * 8;        // K: natural rows
  const int vd = tid >> 2;                            // V: d-row
  const int ko = (tid & 3) * 8;                       // natural key offset (8 keys)
  const int vs0 = ((tid & 1) << 4) | ((tid & 2) << 1);// slot base: ko 0,8,16,24 -> 0,16,4,20
  const u16* Kbase = K + ((long)b * 1024 + kk) * ldk + h * 64 + dc;
  const u16* Vbase = VT + ((long)((b * 8 + h) * 64 + vd)) * 1024 + ko;

  f32x4 o[NQF][4];
  f32x4 lacc[NQF];
#pragma unroll
  for (int qi = 0; qi < NQF; ++qi) {
    lacc[qi] = f32x4{0.f, 0.f, 0.f, 0.f};
#pragma unroll
    for (int j = 0; j < 4; ++j) o[qi][j] = f32x4{0.f, 0.f, 0.f, 0.f};
  }

  // prefetch tile 0
  u32x4 kreg = *(const u32x4*)(Kbase);
  u32x4 vreg = *(const u32x4*)(Vbase);

  for (int k0 = 0; k0 < 1024; k0 += 32) {
    // commit staged regs for THIS tile (V: keys ko..+3 -> slots vs0..+3, ko+4..+7 -> vs0+8..+11)
    *(u32x4*)(&Kt[kk][dc]) = kreg;
    u32x2 vlo = {vreg[0], vreg[1]}, vhi = {vreg[2], vreg[3]};
    *(u32x2*)(&Vt[vd][vs0]) = vlo;
    *(u32x2*)(&Vt[vd][vs0 + 8]) = vhi;
    __syncthreads();
    if (k0 + 32 < 1024) {
      kreg = *(const u32x4*)(Kbase + (long)(k0 + 32) * ldk);
      vreg = *(const u32x4*)(Vbase + (k0 + 32));
    }

    // S^T = K.Q^T: A = K-frag (m=key), B = Q-frag (n=q); chain d-halves
    f32x4 st[2][NQF];
#pragma unroll
    for (int kt = 0; kt < 2; ++kt) {
      bf16x8 ka0 = as_bf(*(const u16x8*)(&Kt[kt * 16 + ln15][q8]));
      bf16x8 ka1 = as_bf(*(const u16x8*)(&Kt[kt * 16 + ln15][32 + q8]));
#pragma unroll
      for (int qi = 0; qi < NQF; ++qi) {
        f32x4 z = f32x4{0.f, 0.f, 0.f, 0.f};
        z = mfma16(ka0, qf[qi][0], z);
        z = mfma16(ka1, qf[qi][1], z);
        st[kt][qi] = z;
      }
    }

    // p = exp2(s^T); assemble PV B-frag IN REGISTERS (slot j<4 = kt0 reg j, j>=4 = kt1)
    bf16x8 pb[NQF];
#pragma unroll
    for (int qi = 0; qi < NQF; ++qi) {
      float p00 = __builtin_amdgcn_exp2f(st[0][qi][0]);
      float p01 = __builtin_amdgcn_exp2f(st[0][qi][1]);
      float p02 = __builtin_amdgcn_exp2f(st[0][qi][2]);
      float p03 = __builtin_amdgcn_exp2f(st[0][qi][3]);
      float p10 = __builtin_amdgcn_exp2f(st[1][qi][0]);
      float p11 = __builtin_amdgcn_exp2f(st[1][qi][1]);
      float p12 = __builtin_amdgcn_exp2f(st[1][qi][2]);
      float p13 = __builtin_amdgcn_exp2f(st[1][qi][3]);
      u32x4 pk;
      pk[0] = pack_bf2(p00, p01);
      pk[1] = pack_bf2(p02, p03);
      pk[2] = pack_bf2(p10, p11);
      pk[3] = pack_bf2(p12, p13);
      pb[qi] = as_bf(__builtin_bit_cast(u16x8, pk));
      lacc[qi] = mfma16(onesb, pb[qi], lacc[qi]);  // l[q] in every C row
    }
    // PV: O^T[d][q]; A = V^T slot-permuted (b128), B = pb
#pragma unroll
    for (int j = 0; j < 4; ++j) {
      bf16x8 av = as_bf(*(const u16x8*)(&Vt[j * 16 + ln15][q8]));
#pragma unroll
      for (int qi = 0; qi < NQF; ++qi) o[qi][j] = mfma16(av, pb[qi], o[qi][j]);
    }
    __syncthreads();  // protect Kt/Vt before next commit
  }

  // normalize + store ctx bf16: O^T C-layout col=q=ln15, row=d=j*16+quad*4+r
#pragma unroll
  for (int qi = 0; qi < NQF; ++qi) {
    float inv = outscale / lacc[qi][0];
    long row = qrow + qi * 16 + ln15;
#pragma unroll
    for (int j = 0; j < 4; ++j) {
      u16x4 ov;
#pragma unroll
      for (int r = 0; r < 4; ++r) ov[r] = f2bf(o[qi][j][r] * inv);
      *(u16x4*)(O + row * ldo + h * 64 + j * 16 + quad * 4) = ov;
    }
  }
}

extern "C" void kernel_launch(void* const* d_in, const int* in_sizes, int n_in,
                              void* d_out, int out_size, void* d_ws, size_t ws_size,
                              hipStream_t stream) {
  const float* hidden = (const float*)d_in[0];
  const float* text   = (const float*)d_in[1];
  const float* wqi = (const float*)d_in[2];  const float* bqi = (const float*)d_in[3];
  const float* wki = (const float*)d_in[4];  const float* bki = (const float*)d_in[5];
  const float* wvi = (const float*)d_in[6];  const float* bvi = (const float*)d_in[7];
  const float* wqt = (const float*)d_in[8];  const float* bqt = (const float*)d_in[9];
  const float* wkt = (const float*)d_in[10]; const float* bkt = (const float*)d_in[11];
  const float* wvt = (const float*)d_in[12]; const float* bvt = (const float*)d_in[13];
  const float* woi = (const float*)d_in[14]; const float* boi = (const float*)d_in[15];
  const float* wot = (const float*)d_in[16]; const float* bot = (const float*)d_in[17];
  const float* wc  = (const float*)d_in[18]; const float* bc  = (const float*)d_in[19];
  const float* wip = (const float*)d_in[20]; const float* bip = (const float*)d_in[21];
  const float* wop = (const float*)d_in[22]; const float* bop = (const float*)d_in[23];

  char* ws = (char*)d_ws;
  u16* XH    = (u16*)(ws + WS_XH);
  u16* XT    = (u16*)(ws + WS_XT);
  u16* WB    = (u16*)(ws + WS_W);
  float* BQI = (float*)(ws + WS_BQI);
  float* BQT = (float*)(ws + WS_BQT);
  u16* QKVI  = (u16*)(ws + WS_QKVI);
  u16* QKVT  = (u16*)(ws + WS_QKVT);
  u16* VTI   = (u16*)(ws + WS_VTI);
  u16* VTT   = (u16*)(ws + WS_VTT);
  u16* CTXIA = (u16*)(ws + WS_CTXIA);
  u16* CTXIB = (u16*)(ws + WS_XH);    // XH dead after QKV GEMMs
  u16* CTXTA = (u16*)(ws + WS_CTXTA);
  u16* CTXTB = (u16*)(ws + WS_XT);    // XT dead after QKV GEMMs
  u16* OCAT  = (u16*)(ws + WS_OCAT);
  u16* OUT2  = (u16*)(ws + WS_OUT2);
  u16* QKVP  = (u16*)(ws + WS_QKVP);
  u16* VTP   = (u16*)(ws + WS_VTP);
  u16* CTXP  = (u16*)(ws + WS_CTXP);

  u16* WQKVI = WB;                 // [1536][512]
  u16* WQKVT = WB + 786432;
  u16* WOUTI = WB + 1572864;
  u16* WOUTT = WB + 1835008;
  u16* WCAT  = WB + 2097152;
  u16* WINP  = WB + 2621440;
  u16* WOUTP = WB + 3407872;

  const int NACT = 8192 * 512;

  // 1. convert activations + weights
  cvt_f32_bf16<<<dim3(NACT / 1024), 256, 0, stream>>>(hidden, XH, NACT);
  cvt_f32_bf16<<<dim3(NACT / 1024), 256, 0, stream>>>(text, XT, NACT);
  prep_weights<<<dim3(14348), 256, 0, stream>>>(wqi, wki, wvi, wqt, wkt, wvt, woi, wot,
                                                wc, wip, wop, bqi, bki, bvi, bqt, bkt, bvt,
                                                WB, BQI, BQT);
  // 2. fused QKV GEMMs (Q cols pre-scaled; V tiles written transposed to VT by epilogue)
  gemm_bf16<4><<<dim3(64, 12), 256, 0, stream>>>(XH, nullptr, 512, WQKVI, BQI, QKVI, 1536, 0,
                                                 512, 0, 512, SCALE_LOG2E_O8, VTI);
  gemm_bf16<4><<<dim3(64, 12), 256, 0, stream>>>(XT, nullptr, 512, WQKVT, BQT, QKVT, 1536, 0,
                                                 512, 0, 512, SCALE_LOG2E_O8, VTT);
  // 3. dual attentions, phase-split (img-q: img-keys->CTXIA, txt-keys->CTXIB; txt-q sym.)
  attn_flash<2><<<dim3(16, 8, 8), 256, 0, stream>>>(QKVI, 1536, QKVI + 512, VTI,
                                                    QKVT + 512, VTT, 1536,
                                                    CTXIA, CTXIB, 512, 0.5f);
  attn_flash<2><<<dim3(16, 8, 8), 256, 0, stream>>>(QKVT, 1536, QKVT + 512, VTT,
                                                    QKVI + 512, VTI, 1536,
                                                    CTXTA, CTXTB, 512, 0.5f);
  // 4. out projections (A + A2 merge) -> concat buffer  [64x64 tiles: 1024 blocks, 4/CU]
  gemm_bf16<2><<<dim3(128, 8), 256, 0, stream>>>(CTXIA, CTXIB, 512, WOUTI, boi, OCAT, 1024, 0,
                                                 512, 0, 0, 1.0f, nullptr);
  gemm_bf16<2><<<dim3(128, 8), 256, 0, stream>>>(CTXTA, CTXTB, 512, WOUTT, bot, OCAT, 1024, 512,
                                                 512, 0, 0, 1.0f, nullptr);
  // 5. cat GEMM (K=1024)  [64x64 tiles]
  gemm_bf16<2><<<dim3(128, 8), 256, 0, stream>>>(OCAT, nullptr, 1024, WCAT, bc, OUT2, 512, 0,
                                                 1024, 0, 0, 1.0f, nullptr);
  // 6. pooled in_proj (Q cols pre-scaled; V -> VTP via epilogue)
  gemm_bf16<4><<<dim3(64, 12), 256, 0, stream>>>(OUT2, nullptr, 512, WINP, bip, QKVP, 1536, 0,
                                                 512, 0, 512, SCALE_LOG2E_O8, VTP);
  // 7. pooled attention (single phase, NQF=1, 16 qtiles)
  attn_flash<1><<<dim3(16, 8, 8), 256, 0, stream>>>(QKVP, 1536, QKVP + 512, VTP,
                                                    nullptr, nullptr, 1536,
                                                    CTXP, nullptr, 512, 1.0f);
  // 8. final out_proj -> d_out (FP32! reference output dtype is float32)  [64x64 tiles]
  gemm_bf16<2><<<dim3(128, 8), 256, 0, stream>>>(CTXP, nullptr, 512, WOUTP, bop, (u16*)d_out,
                                                 512, 0, 512, 1, 0, 1.0f, nullptr);
}

// Round 11
// 425.395 us; speedup vs baseline: 1.0452x; 1.0452x over previous
//
#include <hip/hip_runtime.h>

typedef unsigned short u16;
typedef __attribute__((ext_vector_type(4))) unsigned short u16x4;
typedef __attribute__((ext_vector_type(8))) unsigned short u16x8;
typedef __attribute__((ext_vector_type(4))) float f32x4;
typedef __attribute__((ext_vector_type(8))) __bf16 bf16x8;
typedef __attribute__((ext_vector_type(2))) unsigned int u32x2;
typedef __attribute__((ext_vector_type(4))) unsigned int u32x4;

// ---- workspace layout (bytes) ----
#define WS_XH    0UL          // hidden bf16 [8192][512]; dead after QKV GEMMs -> reused as CTXIB
#define WS_XT    8388608UL    // text bf16; dead after QKV GEMMs -> reused as CTXTB
#define WS_W     16777216UL   // all weights bf16, contiguous (see prep_weights)
#define WS_BQI   24117248UL   // concat bias qkv_img fp32 [1536]
#define WS_BQT   24123392UL   // concat bias qkv_txt fp32 [1536]
#define WS_QKVI  24129536UL   // qkv_img bf16 [8192][1536] (V cols never written; Q pre-scaled)
#define WS_QKVT  49295360UL   // qkv_txt bf16
#define WS_VTI   74461184UL   // v_img^T bf16 [8*8*64][1024]  (written by GEMM epilogue)
#define WS_VTT   82849792UL   // v_txt^T
#define WS_CTXIA 91238400UL   // ctx img, img-key phase, bf16 [8192][512] (*0.5)
#define WS_CTXTA 99627008UL   // ctx txt, txt-key phase
#define WS_OCAT  108015616UL  // concat out bf16 [8192][1024]
// reuse of QKV_I/QKV_T region after attentions complete:
#define WS_OUT2  24129536UL   // out after w_cat bf16 [8192][512]
#define WS_QKVP  32518144UL   // pooled qkv bf16 [8192][1536]
#define WS_VTP   57683968UL   // v_pool^T
#define WS_CTXP  66072576UL   // ctx_pool bf16 [8192][512]

#define SCALE_LOG2E_O8 0.18033688011112042f  // log2(e)/8

__device__ __forceinline__ u16 f2bf(float f) {
  unsigned u = __float_as_uint(f);
  u += 0x7fffu + ((u >> 16) & 1u);   // RNE
  return (u16)(u >> 16);
}
__device__ __forceinline__ float bf2f(u16 v) {
  return __uint_as_float(((unsigned)v) << 16);
}
__device__ __forceinline__ bf16x8 as_bf(u16x8 v) { return __builtin_bit_cast(bf16x8, v); }
__device__ __forceinline__ f32x4 mfma16(bf16x8 a, bf16x8 b, f32x4 c) {
  return __builtin_amdgcn_mfma_f32_16x16x32_bf16(a, b, c, 0, 0, 0);
}
// pack two fp32 into one u32 holding two bf16 (round-half-up)
__device__ __forceinline__ unsigned pack_bf2(float lo, float hi) {
  unsigned a = __float_as_uint(lo) + 0x8000u;
  unsigned b = __float_as_uint(hi) + 0x8000u;
  return __builtin_amdgcn_perm(b, a, 0x07060302);
}

// ---------------- fp32 -> bf16 activation convert ----------------
__global__ __launch_bounds__(256) void cvt_f32_bf16(const float* __restrict__ s,
                                                    u16* __restrict__ d, int n) {
  int i = (blockIdx.x * 256 + threadIdx.x) * 4;
  if (i >= n) return;
  float4 v = *(const float4*)(s + i);
  u16x4 o;
  o[0] = f2bf(v.x); o[1] = f2bf(v.y); o[2] = f2bf(v.z); o[3] = f2bf(v.w);
  *(u16x4*)(d + i) = o;
}

// ---------------- weight prep: convert+concat all weights / biases ----------------
__global__ __launch_bounds__(256) void prep_weights(
    const float* __restrict__ wqi, const float* __restrict__ wki, const float* __restrict__ wvi,
    const float* __restrict__ wqt, const float* __restrict__ wkt, const float* __restrict__ wvt,
    const float* __restrict__ woi, const float* __restrict__ wot,
    const float* __restrict__ wc,  const float* __restrict__ wip, const float* __restrict__ wop,
    const float* __restrict__ bqi, const float* __restrict__ bki, const float* __restrict__ bvi,
    const float* __restrict__ bqt, const float* __restrict__ bkt, const float* __restrict__ bvt,
    u16* __restrict__ wdst, float* __restrict__ bi, float* __restrict__ bt) {
  int i = blockIdx.x * 256 + threadIdx.x;
  if (i < 786432) {
    const float* s = i < 262144 ? wqi : (i < 524288 ? wki : wvi);
    wdst[i] = f2bf(s[i & 262143]);
  } else if (i < 1572864) {
    int j = i - 786432;
    const float* s = j < 262144 ? wqt : (j < 524288 ? wkt : wvt);
    wdst[i] = f2bf(s[j & 262143]);
  } else if (i < 1835008) wdst[i] = f2bf(woi[i - 1572864]);
  else if (i < 2097152)   wdst[i] = f2bf(wot[i - 1835008]);
  else if (i < 2621440)   wdst[i] = f2bf(wc [i - 2097152]);
  else if (i < 3407872)   wdst[i] = f2bf(wip[i - 2621440]);
  else if (i < 3670016)   wdst[i] = f2bf(wop[i - 3407872]);
  else if (i < 3671552) {
    int j = i - 3670016;
    bi[j] = j < 512 ? bqi[j] : (j < 1024 ? bki[j - 512] : bvi[j - 1024]);
  } else if (i < 3673088) {
    int j = i - 3671552;
    bt[j] = j < 512 ? bqt[j] : (j < 1024 ? bkt[j - 512] : bvt[j - 1024]);
  }
}

// ---------------- GEMM: C[M,N] = (A [+ A2])[M,K](bf16) @ W[N,K]^T + bias(f32) ----------------
// Asymmetric templated tile: 4 waves as 2x2, wave covers WFM x WFN frags (16-units) ->
// tile (32*WFM) x (32*WFN). <4,4>: 128x128 (QKV/in_proj; 768 blocks = 3/CU).
// <2,4>: 64x128 for the N=512 GEMMs -> grid (128,4) = 512 blocks = 2/CU WITHOUT raising
// A-side HBM traffic (R10 lesson: 64x64 quartered per-block work and doubled A traffic ->
// regressed; 64x128 keeps A reads identical to 128x128, only re-reads the L2-resident W).
// Register staging + double-buffered LDS, one barrier per K-iter; prefetched register
// loads fly across the compute phase (global_load_lds would drain vmcnt(0) at barrier).
// Permuted lane-linear LDS layout: block = 16 rows x 32k, chunk = lane*16B; writes and
// fragment reads both lane-linear b128, conflict-free.
// vtout (<4,4>, nullable): column tiles n0>=1024 (V third of QKV) stored TRANSPOSED to
// vtout[(b*8+h)*64+d][l] (C-layout regs = 4 consecutive VT cols) -- no transpose pass.
// A2 (nullable): elementwise bf16 add merged at commit. Columns < qcols scaled by qscale
// in fp32 before bf16 quantize. f32out: fp32 C (d_out dtype).
template <int WFM, int WFN>
__global__ __launch_bounds__(256) void gemm_bf16(
    const u16* __restrict__ A, const u16* __restrict__ A2, int lda,
    const u16* __restrict__ W,
    const float* __restrict__ bias, u16* __restrict__ C, int ldc, int coff, int K,
    int f32out, int qcols, float qscale, u16* __restrict__ vtout) {
  constexpr int NBA = WFM / 2;            // staged 16-row A blocks per wave
  constexpr int NBW = WFN / 2;            // staged 16-row W blocks per wave
  __shared__ __align__(16) u16 As[2][4 * NBA * 512];
  __shared__ __align__(16) u16 Bs[2][4 * NBW * 512];
  const int tid = threadIdx.x, lane = tid & 63, wv = tid >> 6;
  const int wm = wv >> 1, wn = wv & 1;
  const int ln15 = lane & 15;
  const int m0 = blockIdx.x * (32 * WFM), n0 = blockIdx.y * (32 * WFN);

  const int srow = lane & 15, skc = lane >> 4;
  const u16* gA[NBA];
  const u16* gA2[NBA];
  const u16* gW[NBW];
#pragma unroll
  for (int c = 0; c < NBA; ++c) {
    gA[c] = A + (long)(m0 + wv * (16 * NBA) + c * 16 + srow) * lda + skc * 8;
    gA2[c] = A2 + (long)(m0 + wv * (16 * NBA) + c * 16 + srow) * lda + skc * 8;  // if A2
  }
#pragma unroll
  for (int c = 0; c < NBW; ++c)
    gW[c] = W + (long)(n0 + wv * (16 * NBW) + c * 16 + srow) * K + skc * 8;

  f32x4 acc[WFM][WFN];
#pragma unroll
  for (int j = 0; j < WFN; ++j) {
    float bv = bias[n0 + wn * (16 * WFN) + j * 16 + ln15];
#pragma unroll
    for (int i = 0; i < WFM; ++i) acc[i][j] = f32x4{bv, bv, bv, bv};
  }

  // prologue: tile 0 into registers
  u16x8 ra[NBA], rc[NBA], rb[NBW];
#pragma unroll
  for (int c = 0; c < NBA; ++c) {
    ra[c] = *(const u16x8*)(gA[c]);
    if (A2) rc[c] = *(const u16x8*)(gA2[c]);
  }
#pragma unroll
  for (int c = 0; c < NBW; ++c) rb[c] = *(const u16x8*)(gW[c]);

  int buf = 0;
  for (int k0 = 0; k0 < K; k0 += 32, buf ^= 1) {
#pragma unroll
    for (int c = 0; c < NBA; ++c) {
      u16x8 wa = ra[c];
      if (A2) {
#pragma unroll
        for (int u = 0; u < 8; ++u) wa[u] = f2bf(bf2f(ra[c][u]) + bf2f(rc[c][u]));
      }
      *(u16x8*)(As[buf] + (wv * NBA + c) * 512 + lane * 8) = wa;
    }
#pragma unroll
    for (int c = 0; c < NBW; ++c)
      *(u16x8*)(Bs[buf] + (wv * NBW + c) * 512 + lane * 8) = rb[c];
    if (k0 + 32 < K) {
#pragma unroll
      for (int c = 0; c < NBA; ++c) {
        ra[c] = *(const u16x8*)(gA[c] + k0 + 32);
        if (A2) rc[c] = *(const u16x8*)(gA2[c] + k0 + 32);
      }
#pragma unroll
      for (int c = 0; c < NBW; ++c) rb[c] = *(const u16x8*)(gW[c] + k0 + 32);
    }
    __syncthreads();

    bf16x8 af[WFM], bfr[WFN];
#pragma unroll
    for (int i = 0; i < WFM; ++i)
      af[i] = as_bf(*(const u16x8*)(As[buf] + (wm * WFM + i) * 512 + lane * 8));
#pragma unroll
    for (int j = 0; j < WFN; ++j)
      bfr[j] = as_bf(*(const u16x8*)(Bs[buf] + (wn * WFN + j) * 512 + lane * 8));
#pragma unroll
    for (int i = 0; i < WFM; ++i)
#pragma unroll
      for (int j = 0; j < WFN; ++j) acc[i][j] = mfma16(af[i], bfr[j], acc[i][j]);
  }
  // epilogue: C/D layout col=lane&15, row=quad*4+reg (m89/m91 verified)
  const int quad = lane >> 4;
  const int qr4 = quad * 4;
  if (WFM == 4 && WFN == 4 && vtout && n0 >= 1024) {
    // V tile -> transposed store into VT[(b*8+h)*64+d][l]
#pragma unroll
    for (int j = 0; j < WFN; ++j) {
      int col = n0 + wn * (16 * WFN) + j * 16 + ln15;    // 1024..1535
      int dg = col - 1024;
#pragma unroll
      for (int i = 0; i < WFM; ++i) {
        int row0 = m0 + wm * (16 * WFM) + i * 16 + qr4;  // 4 consecutive C-rows = 4 VT cols
        long vr = ((long)(row0 >> 10) * 8 + (dg >> 6)) * 64 + (dg & 63);
        u16x4 ov;
#pragma unroll
        for (int r = 0; r < 4; ++r) ov[r] = f2bf(acc[i][j][r]);
        *(u16x4*)(vtout + vr * 1024 + (row0 & 1023)) = ov;
      }
    }
    return;
  }
  float colsc[WFN];
#pragma unroll
  for (int j = 0; j < WFN; ++j)
    colsc[j] = (n0 + wn * (16 * WFN) + j * 16 < qcols) ? qscale : 1.0f;
#pragma unroll
  for (int i = 0; i < WFM; ++i)
#pragma unroll
    for (int r = 0; r < 4; ++r) {
      int row = m0 + wm * (16 * WFM) + i * 16 + qr4 + r;
      long cidx = (long)row * ldc + coff + n0 + wn * (16 * WFN) + ln15;
      if (f32out) {
        float* cf = (float*)C + cidx;
#pragma unroll
        for (int j = 0; j < WFN; ++j) cf[j * 16] = acc[i][j][r] * colsc[j];
      } else {
        u16* cp = C + cidx;
#pragma unroll
        for (int j = 0; j < WFN; ++j) cp[j * 16] = f2bf(acc[i][j][r] * colsc[j]);
      }
    }
}

// ---------------- flash attention, S^T formulation: NO P LDS round-trip ----------------
// Compute S^T = K.Q^T (A=K-frag from Kt, B=Q-frag). S^T C-layout (q=ln15, keys=quad*4+r
// per 16-key tile) IS a PV B-fragment under the fixed key permutation
// slot(quad*8+j) <-> key (j<4 ? 4q+j : 16+4q+j-4): P packs entirely in registers.
// PV computes O^T = V^T.P^T, A=V^T b128 from slot-permuted Vt (permutation at staging,
// 2xb64). l = ones.P^T via 1 MFMA (same bf16 P as PV -> bias cancels in O=o/l).
// Phase-split dual (blockIdx.x = qtile|phase). K/V tile k+1 prefetched into registers.
// No-max softmax (Q pre-scaled by log2e/8 at GEMM); raw v_exp_f32.
template <int NQF>
__global__ __launch_bounds__(256) void attn_flash(
    const u16* __restrict__ Q, int ldq,
    const u16* __restrict__ KA, const u16* __restrict__ VTA,
    const u16* __restrict__ KB, const u16* __restrict__ VTB, int ldk,
    u16* __restrict__ OA, u16* __restrict__ OB, int ldo, float outscale) {
  __shared__ __align__(16) u16 Kt[32][72];   // K tile, natural key order [key][d]
  __shared__ __align__(16) u16 Vt[64][40];   // V^T tile, slot-permuted key order [d][slot]
  const int tid = threadIdx.x, lane = tid & 63, wv = tid >> 6;
  const int ln15 = lane & 15, quad = lane >> 4, q8 = quad * 8;
  const int h = blockIdx.y, b = blockIdx.z;

  const u16 *K, *VT;
  u16* O;
  int qtile;
  if (KB != nullptr) {
    qtile = blockIdx.x >> 1;
    int phase = blockIdx.x & 1;
    K = phase ? KB : KA;
    VT = phase ? VTB : VTA;
    O = phase ? OB : OA;
  } else {
    qtile = blockIdx.x;
    K = KA; VT = VTA; O = OA;
  }
  const long qrow = (long)b * 1024 + qtile * (NQF * 64) + wv * (NQF * 16);

  // Q fragments (MFMA B operand: n=lane&15=q, k=quad*8+j=d) [qi][d-half]
  bf16x8 qf[NQF][2];
#pragma unroll
  for (int qi = 0; qi < NQF; ++qi) {
    const u16* qp = Q + (qrow + qi * 16 + ln15) * ldq + h * 64;
    qf[qi][0] = as_bf(*(const u16x8*)(qp + q8));
    qf[qi][1] = as_bf(*(const u16x8*)(qp + 32 + q8));
  }

  u16x8 ones_u;
#pragma unroll
  for (int j = 0; j < 8; ++j) ones_u[j] = 0x3F80;  // bf16 1.0
  const bf16x8 onesb = as_bf(ones_u);

  // staging thread->element maps
  const int kk = tid >> 3, dc = (tid & 7) * 8;        // K: natural rows
  const int vd = tid >> 2;                            // V: d-row
  const int ko = (tid & 3) * 8;                       // natural key offset (8 keys)
  const int vs0 = ((tid & 1) << 4) | ((tid & 2) << 1);// slot base: ko 0,8,16,24 -> 0,16,4,20
  const u16* Kbase = K + ((long)b * 1024 + kk) * ldk + h * 64 + dc;
  const u16* Vbase = VT + ((long)((b * 8 + h) * 64 + vd)) * 1024 + ko;

  f32x4 o[NQF][4];
  f32x4 lacc[NQF];
#pragma unroll
  for (int qi = 0; qi < NQF; ++qi) {
    lacc[qi] = f32x4{0.f, 0.f, 0.f, 0.f};
#pragma unroll
    for (int j = 0; j < 4; ++j) o[qi][j] = f32x4{0.f, 0.f, 0.f, 0.f};
  }

  // prefetch tile 0
  u32x4 kreg = *(const u32x4*)(Kbase);
  u32x4 vreg = *(const u32x4*)(Vbase);

  for (int k0 = 0; k0 < 1024; k0 += 32) {
    // commit staged regs for THIS tile (V: keys ko..+3 -> slots vs0..+3, ko+4..+7 -> vs0+8..+11)
    *(u32x4*)(&Kt[kk][dc]) = kreg;
    u32x2 vlo = {vreg[0], vreg[1]}, vhi = {vreg[2], vreg[3]};
    *(u32x2*)(&Vt[vd][vs0]) = vlo;
    *(u32x2*)(&Vt[vd][vs0 + 8]) = vhi;
    __syncthreads();
    if (k0 + 32 < 1024) {
      kreg = *(const u32x4*)(Kbase + (long)(k0 + 32) * ldk);
      vreg = *(const u32x4*)(Vbase + (k0 + 32));
    }

    // S^T = K.Q^T: A = K-frag (m=key), B = Q-frag (n=q); chain d-halves
    f32x4 st[2][NQF];
#pragma unroll
    for (int kt = 0; kt < 2; ++kt) {
      bf16x8 ka0 = as_bf(*(const u16x8*)(&Kt[kt * 16 + ln15][q8]));
      bf16x8 ka1 = as_bf(*(const u16x8*)(&Kt[kt * 16 + ln15][32 + q8]));
#pragma unroll
      for (int qi = 0; qi < NQF; ++qi) {
        f32x4 z = f32x4{0.f, 0.f, 0.f, 0.f};
        z = mfma16(ka0, qf[qi][0], z);
        z = mfma16(ka1, qf[qi][1], z);
        st[kt][qi] = z;
      }
    }

    // p = exp2(s^T); assemble PV B-frag IN REGISTERS (slot j<4 = kt0 reg j, j>=4 = kt1)
    bf16x8 pb[NQF];
#pragma unroll
    for (int qi = 0; qi < NQF; ++qi) {
      float p00 = __builtin_amdgcn_exp2f(st[0][qi][0]);
      float p01 = __builtin_amdgcn_exp2f(st[0][qi][1]);
      float p02 = __builtin_amdgcn_exp2f(st[0][qi][2]);
      float p03 = __builtin_amdgcn_exp2f(st[0][qi][3]);
      float p10 = __builtin_amdgcn_exp2f(st[1][qi][0]);
      float p11 = __builtin_amdgcn_exp2f(st[1][qi][1]);
      float p12 = __builtin_amdgcn_exp2f(st[1][qi][2]);
      float p13 = __builtin_amdgcn_exp2f(st[1][qi][3]);
      u32x4 pk;
      pk[0] = pack_bf2(p00, p01);
      pk[1] = pack_bf2(p02, p03);
      pk[2] = pack_bf2(p10, p11);
      pk[3] = pack_bf2(p12, p13);
      pb[qi] = as_bf(__builtin_bit_cast(u16x8, pk));
      lacc[qi] = mfma16(onesb, pb[qi], lacc[qi]);  // l[q] in every C row
    }
    // PV: O^T[d][q]; A = V^T slot-permuted (b128), B = pb
#pragma unroll
    for (int j = 0; j < 4; ++j) {
      bf16x8 av = as_bf(*(const u16x8*)(&Vt[j * 16 + ln15][q8]));
#pragma unroll
      for (int qi = 0; qi < NQF; ++qi) o[qi][j] = mfma16(av, pb[qi], o[qi][j]);
    }
    __syncthreads();  // protect Kt/Vt before next commit
  }

  // normalize + store ctx bf16: O^T C-layout col=q=ln15, row=d=j*16+quad*4+r
#pragma unroll
  for (int qi = 0; qi < NQF; ++qi) {
    float inv = outscale / lacc[qi][0];
    long row = qrow + qi * 16 + ln15;
#pragma unroll
    for (int j = 0; j < 4; ++j) {
      u16x4 ov;
#pragma unroll
      for (int r = 0; r < 4; ++r) ov[r] = f2bf(o[qi][j][r] * inv);
      *(u16x4*)(O + row * ldo + h * 64 + j * 16 + quad * 4) = ov;
    }
  }
}

extern "C" void kernel_launch(void* const* d_in, const int* in_sizes, int n_in,
                              void* d_out, int out_size, void* d_ws, size_t ws_size,
                              hipStream_t stream) {
  const float* hidden = (const float*)d_in[0];
  const float* text   = (const float*)d_in[1];
  const float* wqi = (const float*)d_in[2];  const float* bqi = (const float*)d_in[3];
  const float* wki = (const float*)d_in[4];  const float* bki = (const float*)d_in[5];
  const float* wvi = (const float*)d_in[6];  const float* bvi = (const float*)d_in[7];
  const float* wqt = (const float*)d_in[8];  const float* bqt = (const float*)d_in[9];
  const float* wkt = (const float*)d_in[10]; const float* bkt = (const float*)d_in[11];
  const float* wvt = (const float*)d_in[12]; const float* bvt = (const float*)d_in[13];
  const float* woi = (const float*)d_in[14]; const float* boi = (const float*)d_in[15];
  const float* wot = (const float*)d_in[16]; const float* bot = (const float*)d_in[17];
  const float* wc  = (const float*)d_in[18]; const float* bc  = (const float*)d_in[19];
  const float* wip = (const float*)d_in[20]; const float* bip = (const float*)d_in[21];
  const float* wop = (const float*)d_in[22]; const float* bop = (const float*)d_in[23];

  char* ws = (char*)d_ws;
  u16* XH    = (u16*)(ws + WS_XH);
  u16* XT    = (u16*)(ws + WS_XT);
  u16* WB    = (u16*)(ws + WS_W);
  float* BQI = (float*)(ws + WS_BQI);
  float* BQT = (float*)(ws + WS_BQT);
  u16* QKVI  = (u16*)(ws + WS_QKVI);
  u16* QKVT  = (u16*)(ws + WS_QKVT);
  u16* VTI   = (u16*)(ws + WS_VTI);
  u16* VTT   = (u16*)(ws + WS_VTT);
  u16* CTXIA = (u16*)(ws + WS_CTXIA);
  u16* CTXIB = (u16*)(ws + WS_XH);    // XH dead after QKV GEMMs
  u16* CTXTA = (u16*)(ws + WS_CTXTA);
  u16* CTXTB = (u16*)(ws + WS_XT);    // XT dead after QKV GEMMs
  u16* OCAT  = (u16*)(ws + WS_OCAT);
  u16* OUT2  = (u16*)(ws + WS_OUT2);
  u16* QKVP  = (u16*)(ws + WS_QKVP);
  u16* VTP   = (u16*)(ws + WS_VTP);
  u16* CTXP  = (u16*)(ws + WS_CTXP);

  u16* WQKVI = WB;                 // [1536][512]
  u16* WQKVT = WB + 786432;
  u16* WOUTI = WB + 1572864;
  u16* WOUTT = WB + 1835008;
  u16* WCAT  = WB + 2097152;
  u16* WINP  = WB + 2621440;
  u16* WOUTP = WB + 3407872;

  const int NACT = 8192 * 512;

  // 1. convert activations + weights
  cvt_f32_bf16<<<dim3(NACT / 1024), 256, 0, stream>>>(hidden, XH, NACT);
  cvt_f32_bf16<<<dim3(NACT / 1024), 256, 0, stream>>>(text, XT, NACT);
  prep_weights<<<dim3(14348), 256, 0, stream>>>(wqi, wki, wvi, wqt, wkt, wvt, woi, wot,
                                                wc, wip, wop, bqi, bki, bvi, bqt, bkt, bvt,
                                                WB, BQI, BQT);
  // 2. fused QKV GEMMs (Q cols pre-scaled; V tiles written transposed to VT by epilogue)
  gemm_bf16<4, 4><<<dim3(64, 12), 256, 0, stream>>>(XH, nullptr, 512, WQKVI, BQI, QKVI, 1536, 0,
                                                    512, 0, 512, SCALE_LOG2E_O8, VTI);
  gemm_bf16<4, 4><<<dim3(64, 12), 256, 0, stream>>>(XT, nullptr, 512, WQKVT, BQT, QKVT, 1536, 0,
                                                    512, 0, 512, SCALE_LOG2E_O8, VTT);
  // 3. dual attentions, phase-split (img-q: img-keys->CTXIA, txt-keys->CTXIB; txt-q sym.)
  attn_flash<2><<<dim3(16, 8, 8), 256, 0, stream>>>(QKVI, 1536, QKVI + 512, VTI,
                                                    QKVT + 512, VTT, 1536,
                                                    CTXIA, CTXIB, 512, 0.5f);
  attn_flash<2><<<dim3(16, 8, 8), 256, 0, stream>>>(QKVT, 1536, QKVT + 512, VTT,
                                                    QKVI + 512, VTI, 1536,
                                                    CTXTA, CTXTB, 512, 0.5f);
  // 4. out projections (A + A2 merge) -> concat buffer  [64x128 tiles: 512 blocks, 2/CU]
  gemm_bf16<2, 4><<<dim3(128, 4), 256, 0, stream>>>(CTXIA, CTXIB, 512, WOUTI, boi, OCAT, 1024,
                                                    0, 512, 0, 0, 1.0f, nullptr);
  gemm_bf16<2, 4><<<dim3(128, 4), 256, 0, stream>>>(CTXTA, CTXTB, 512, WOUTT, bot, OCAT, 1024,
                                                    512, 512, 0, 0, 1.0f, nullptr);
  // 5. cat GEMM (K=1024)  [64x128 tiles]
  gemm_bf16<2, 4><<<dim3(128, 4), 256, 0, stream>>>(OCAT, nullptr, 1024, WCAT, bc, OUT2, 512,
                                                    0, 1024, 0, 0, 1.0f, nullptr);
  // 6. pooled in_proj (Q cols pre-scaled; V -> VTP via epilogue)
  gemm_bf16<4, 4><<<dim3(64, 12), 256, 0, stream>>>(OUT2, nullptr, 512, WINP, bip, QKVP, 1536,
                                                    0, 512, 0, 512, SCALE_LOG2E_O8, VTP);
  // 7. pooled attention (single phase, NQF=1, 16 qtiles)
  attn_flash<1><<<dim3(16, 8, 8), 256, 0, stream>>>(QKVP, 1536, QKVP + 512, VTP,
                                                    nullptr, nullptr, 1536,
                                                    CTXP, nullptr, 512, 1.0f);
  // 8. final out_proj -> d_out (FP32! reference output dtype is float32)  [64x128 tiles]
  gemm_bf16<2, 4><<<dim3(128, 4), 256, 0, stream>>>(CTXP, nullptr, 512, WOUTP, bop,
                                                    (u16*)d_out, 512, 0, 512, 1, 0, 1.0f,
                                                    nullptr);
}